// Round 2
// baseline (277.507 us; speedup 1.0000x reference)
//
#include <hip/hip_runtime.h>
#include <hip/hip_bf16.h>
#include <stdint.h>

#define NN 16384
#define BM 64
#define BK 64
#define NSTEPS (NN / BK)

typedef __attribute__((ext_vector_type(8))) short bf16x8;   // MFMA A/B frag: 8 bf16
typedef __attribute__((ext_vector_type(4))) float f32x4;    // MFMA C/D frag + raw loads
typedef __attribute__((ext_vector_type(4))) unsigned short u16x4;
typedef __attribute__((ext_vector_type(4))) unsigned int u32x4;

__device__ __forceinline__ unsigned short f2bf(float f) {
    uint32_t u = __builtin_bit_cast(uint32_t, f);
    u += 0x7fffu + ((u >> 16) & 1u);   // RNE; inputs are finite
    return (unsigned short)(u >> 16);
}

// neighT[c][r] = bf16(neigh[r][c]); output-coalesced, reads L2/L3-absorbed (8 MB)
__global__ __launch_bounds__(256) void prep_transpose(const float* __restrict__ src,
                                                      unsigned short* __restrict__ dstT) {
    int gid = blockIdx.x * 256 + threadIdx.x;
    int r = gid & (NN - 1);
    int c = gid >> 14;
    dstT[(size_t)c * NN + r] = f2bf(src[(size_t)r * 128 + c]);
}

#define MFMA16(a, b, c) __builtin_amdgcn_mfma_f32_16x16x32_bf16(a, b, c, 0, 0, 0)

__global__ __launch_bounds__(256, 1) void sage_fused(
    const float* __restrict__ adj,
    const float* __restrict__ feat,
    const unsigned short* __restrict__ neighT,
    const float* __restrict__ W,
    float* __restrict__ out)
{
    // LDS: 16 + 32 + 64 + 32 + 0.25 = 144.25 KB -> 1 block/CU
    __shared__ unsigned short a_lds[2][BM * BK];    // adj tile bf16, swizzled
    __shared__ unsigned short b_lds[2][128 * BK];   // neighT tile [c][k] bf16, swizzled
    __shared__ unsigned short w_lds[128 * 256];     // W bf16 [n][k], swizzled
    __shared__ unsigned short d_lds[BM * 256];      // data = [feat | h] bf16, swizzled
    __shared__ float degp[BM];

    const int t = threadIdx.x;
    const int lane = t & 63;
    const int wv = t >> 6;        // wave 0..3
    const int mt2 = wv >> 1;      // wave row 0..1 (32 rows each)
    const int nt2 = wv & 1;       // wave col 0..1 (64 cols each)
    const size_t row0 = (size_t)blockIdx.x * BM;

    if (t < BM) degp[t] = 0.f;

    // --- staging address plan ---
    // A (f32): i=0..3: row = 16*i + (t>>4), float4-slot = t&15 (BK=64 f32 = 16 slots)
    const int ar0 = t >> 4;
    const int acs = (t & 15) * 4;            // float col within BK
    // B (bf16): i=0..3: row(c) = 32*i + (t>>3), 16B-slot = t&7 (BK=64 bf16 = 8 slots)
    const int br0 = t >> 3;
    const int bcs = (t & 7) * 8;             // bf16 col within BK

    const float* aG = adj + (row0 + ar0) * (size_t)NN + acs;
    const unsigned short* bG = neighT + (size_t)br0 * NN + bcs;

    int awb[4], bwb[4];
#pragma unroll
    for (int i = 0; i < 4; ++i) {
        int ar = ar0 + 16 * i;
        awb[i] = ((ar * (BK * 2)) + acs * 2) ^ ((ar & 7) << 4);
        int br = br0 + 32 * i;
        bwb[i] = ((br * (BK * 2)) + bcs * 2) ^ ((br & 7) << 4);
    }

    f32x4 acc[2][4];
#pragma unroll
    for (int i = 0; i < 2; ++i)
#pragma unroll
        for (int j = 0; j < 4; ++j) acc[i][j] = (f32x4){0.f, 0.f, 0.f, 0.f};

    float dsum[4] = {0.f, 0.f, 0.f, 0.f};

    f32x4 ar_[4];
    u32x4 br_[4];

    char* aL = (char*)a_lds;
    char* bL = (char*)b_lds;

    // prologue: load + stage tile 0 into buf 0
#pragma unroll
    for (int i = 0; i < 4; ++i)
        ar_[i] = __builtin_nontemporal_load((const f32x4*)(aG + (size_t)(16 * i) * NN));
#pragma unroll
    for (int i = 0; i < 4; ++i)
        br_[i] = *(const u32x4*)(bG + (size_t)(32 * i) * NN);
#pragma unroll
    for (int i = 0; i < 4; ++i) {
        f32x4 v = ar_[i];
        dsum[i] += (v[0] + v[1]) + (v[2] + v[3]);
        u16x4 p; p.x = f2bf(v[0]); p.y = f2bf(v[1]); p.z = f2bf(v[2]); p.w = f2bf(v[3]);
        *(u16x4*)(aL + awb[i]) = p;
        *(u32x4*)(bL + bwb[i]) = br_[i];
    }

    int cur = 0;
    for (int kt = 0; kt < NSTEPS; ++kt) {
        const bool pf = (kt + 1 < NSTEPS);
        if (pf) {
            const size_t koff = (size_t)(kt + 1) * BK;
#pragma unroll
            for (int i = 0; i < 4; ++i)
                ar_[i] = __builtin_nontemporal_load((const f32x4*)(aG + (size_t)(16 * i) * NN + koff));
#pragma unroll
            for (int i = 0; i < 4; ++i)
                br_[i] = *(const u32x4*)(bG + (size_t)(32 * i) * NN + koff);
        }
        __syncthreads();   // tile kt staged & everyone done reading buf cur^1
        {
            const char* aB = aL + cur * (BM * BK * 2);
            const char* bB = bL + cur * (128 * BK * 2);
#pragma unroll
            for (int ks = 0; ks < 2; ++ks) {
                bf16x8 af[2], bfr[4];
#pragma unroll
                for (int ms = 0; ms < 2; ++ms) {
                    int r = mt2 * 32 + ms * 16 + (lane & 15);
                    int off = (r * (BK * 2) + ks * 64 + (lane >> 4) * 16) ^ ((r & 7) << 4);
                    af[ms] = *(const bf16x8*)(aB + off);
                }
#pragma unroll
                for (int ns = 0; ns < 4; ++ns) {
                    int c = nt2 * 64 + ns * 16 + (lane & 15);
                    int off = (c * (BK * 2) + ks * 64 + (lane >> 4) * 16) ^ ((c & 7) << 4);
                    bfr[ns] = *(const bf16x8*)(bB + off);
                }
#pragma unroll
                for (int ms = 0; ms < 2; ++ms)
#pragma unroll
                    for (int ns = 0; ns < 4; ++ns)
                        acc[ms][ns] = MFMA16(af[ms], bfr[ns], acc[ms][ns]);
            }
        }
        if (pf) {
            char* aW = aL + (cur ^ 1) * (BM * BK * 2);
            char* bW = bL + (cur ^ 1) * (128 * BK * 2);
#pragma unroll
            for (int i = 0; i < 4; ++i) {
                f32x4 v = ar_[i];
                dsum[i] += (v[0] + v[1]) + (v[2] + v[3]);
                u16x4 p; p.x = f2bf(v[0]); p.y = f2bf(v[1]); p.z = f2bf(v[2]); p.w = f2bf(v[3]);
                *(u16x4*)(aW + awb[i]) = p;
                *(u32x4*)(bW + bwb[i]) = br_[i];
            }
        }
        cur ^= 1;
    }

    // ---- degree reduction ----
#pragma unroll
    for (int i = 0; i < 4; ++i)
        atomicAdd(&degp[ar0 + 16 * i], dsum[i]);
    __syncthreads();

    // ---- h = S/deg -> d_lds cols [128,256) ----
    char* dL = (char*)d_lds;
#pragma unroll
    for (int ms = 0; ms < 2; ++ms)
#pragma unroll
        for (int ns = 0; ns < 4; ++ns)
#pragma unroll
            for (int j = 0; j < 4; ++j) {
                int r = mt2 * 32 + ms * 16 + (lane >> 4) * 4 + j;
                int c = 128 + nt2 * 64 + ns * 16 + (lane & 15);
                float v = acc[ms][ns][j] / (degp[r] + 1.0f);
                int off = (r * 512 + c * 2) ^ ((r & 7) << 4);
                *(unsigned short*)(dL + off) = f2bf(v);
            }

    // ---- features -> d_lds cols [0,128) ----
#pragma unroll
    for (int i = 0; i < 8; ++i) {
        int idx = i * 256 + t;
        int r = idx >> 5;          // 32 float4-slots per 128-f32 row
        int s = idx & 31;
        f32x4 v = *(const f32x4*)(feat + (row0 + r) * 128 + s * 4);
        u16x4 p; p.x = f2bf(v[0]); p.y = f2bf(v[1]); p.z = f2bf(v[2]); p.w = f2bf(v[3]);
        int off = (r * 512 + s * 8) ^ ((r & 7) << 4);
        *(u16x4*)(dL + off) = p;
    }
    // ---- W [128][256] f32 -> w_lds bf16 ----
    char* wL = (char*)w_lds;
#pragma unroll
    for (int i = 0; i < 32; ++i) {
        int idx = i * 256 + t;
        int r = idx >> 6;          // 64 float4-slots per 256-f32 row
        int s = idx & 63;
        f32x4 v = *(const f32x4*)(W + r * 256 + s * 4);
        u16x4 p; p.x = f2bf(v[0]); p.y = f2bf(v[1]); p.z = f2bf(v[2]); p.w = f2bf(v[3]);
        int off = (r * 512 + s * 8) ^ ((r & 7) << 4);
        *(u16x4*)(wL + off) = p;
    }
    __syncthreads();

    // ---- out = data(64x256) @ W^T via MFMA, K=256 ----
    f32x4 acc2[2][4];
#pragma unroll
    for (int i = 0; i < 2; ++i)
#pragma unroll
        for (int j = 0; j < 4; ++j) acc2[i][j] = (f32x4){0.f, 0.f, 0.f, 0.f};

#pragma unroll
    for (int ks = 0; ks < 8; ++ks) {
        bf16x8 af[2], bfr[4];
#pragma unroll
        for (int ms = 0; ms < 2; ++ms) {
            int r = mt2 * 32 + ms * 16 + (lane & 15);
            int off = (r * 512 + ks * 64 + (lane >> 4) * 16) ^ ((r & 7) << 4);
            af[ms] = *(const bf16x8*)(dL + off);
        }
#pragma unroll
        for (int ns = 0; ns < 4; ++ns) {
            int c = nt2 * 64 + ns * 16 + (lane & 15);
            int off = (c * 512 + ks * 64 + (lane >> 4) * 16) ^ ((c & 7) << 4);
            bfr[ns] = *(const bf16x8*)(wL + off);
        }
#pragma unroll
        for (int ms = 0; ms < 2; ++ms)
#pragma unroll
            for (int ns = 0; ns < 4; ++ns)
                acc2[ms][ns] = MFMA16(af[ms], bfr[ns], acc2[ms][ns]);
    }

    // ---- store f32 ----
#pragma unroll
    for (int ms = 0; ms < 2; ++ms)
#pragma unroll
        for (int ns = 0; ns < 4; ++ns)
#pragma unroll
            for (int j = 0; j < 4; ++j) {
                int r = mt2 * 32 + ms * 16 + (lane >> 4) * 4 + j;
                int c = nt2 * 64 + ns * 16 + (lane & 15);
                out[(row0 + r) * 128 + c] = acc2[ms][ns][j];
            }
}

extern "C" void kernel_launch(void* const* d_in, const int* in_sizes, int n_in,
                              void* d_out, int out_size, void* d_ws, size_t ws_size,
                              hipStream_t stream) {
    const float* adj = (const float*)d_in[0];
    const float* feat = (const float*)d_in[1];
    const float* neigh = (const float*)d_in[2];
    const float* W = (const float*)d_in[3];
    float* out = (float*)d_out;
    unsigned short* neighT = (unsigned short*)d_ws;   // 128 x 16384 bf16 = 4 MiB

    prep_transpose<<<(NN * 128) / 256, 256, 0, stream>>>(neigh, neighT);
    sage_fused<<<NN / BM, 256, 0, stream>>>(adj, feat, neighT, W, out);
}

// Round 3
// 262.731 us; speedup vs baseline: 1.0562x; 1.0562x over previous
//
#include <hip/hip_runtime.h>
#include <hip/hip_bf16.h>
#include <stdint.h>

#define NN 16384
#define BM 32
#define BK 64
#define NSTEPS (NN / BK)

typedef __attribute__((ext_vector_type(8))) short bf16x8;   // MFMA A/B frag: 8 bf16
typedef __attribute__((ext_vector_type(4))) float f32x4;
typedef __attribute__((ext_vector_type(4))) unsigned short u16x4;
typedef __attribute__((ext_vector_type(8))) unsigned short u16x8;
typedef __attribute__((ext_vector_type(4))) unsigned int u32x4;

__device__ __forceinline__ unsigned short f2bf(float f) {
    uint32_t u = __builtin_bit_cast(uint32_t, f);
    u += 0x7fffu + ((u >> 16) & 1u);   // RNE; inputs are finite
    return (unsigned short)(u >> 16);
}

// Tiled transpose: neighT[c][r] = bf16(neigh[r][c]). Coalesced reads AND writes.
// grid 256 blocks x 256 thr; block b handles rows [b*64, b*64+64) x all 128 cols.
__global__ __launch_bounds__(256) void prep_transpose(const float* __restrict__ src,
                                                      unsigned short* __restrict__ dstT) {
    __shared__ unsigned short tl[128][66];   // [c][r], pad 66 to break bank alias
    const int t = threadIdx.x;
    const int r0 = blockIdx.x * 64;
#pragma unroll
    for (int i = 0; i < 8; ++i) {
        int idx = i * 256 + t;
        int r = idx >> 5;            // 0..63
        int s = idx & 31;            // f32x4 slot within 128-col row
        f32x4 v = *(const f32x4*)(src + (size_t)(r0 + r) * 128 + s * 4);
#pragma unroll
        for (int j = 0; j < 4; ++j) tl[s * 4 + j][r] = f2bf(v[j]);
    }
    __syncthreads();
    const int c = t >> 1;
    const int half = t & 1;
#pragma unroll
    for (int j = 0; j < 4; ++j) {
        u16x8 p;
#pragma unroll
        for (int e = 0; e < 8; ++e) p[e] = tl[c][half * 32 + j * 8 + e];
        *(u16x8*)(dstT + (size_t)c * NN + r0 + half * 32 + j * 8) = p;
    }
}

#define MFMA16(a, b, c) __builtin_amdgcn_mfma_f32_16x16x32_bf16(a, b, c, 0, 0, 0)

__global__ __launch_bounds__(256, 2) void sage_fused(
    const float* __restrict__ adj,
    const float* __restrict__ feat,
    const unsigned short* __restrict__ neighT,
    const float* __restrict__ W,
    float* __restrict__ out)
{
    // LDS: 8 + 32 + 16 + 0.125 = 56.1 KB -> 2 blocks/CU
    __shared__ unsigned short a_lds[2][BM * BK];    // adj tile bf16, swizzled
    __shared__ unsigned short b_lds[2][128 * BK];   // neighT tile [c][k] bf16, swizzled
    __shared__ unsigned short d_lds[BM * 256];      // data = [feat | h] bf16, swizzled
    __shared__ float degp[BM];

    const int t = threadIdx.x;
    const int lane = t & 63;
    const int wv = t >> 6;        // wave 0..3
    const int mt = wv >> 1;       // wave row 0..1 (16 rows each)
    const int nt = wv & 1;        // wave col 0..1 (64 cols each)
    const size_t row0 = (size_t)blockIdx.x * BM;

    if (t < BM) degp[t] = 0.f;

    // A (f32): i=0..1: row = 16*i + (t>>4), float4-slot = t&15
    const int ar0 = t >> 4;
    const int acs = (t & 15) * 4;
    // B (bf16): i=0..3: row(c) = 32*i + (t>>3), 16B-slot = t&7
    const int br0 = t >> 3;
    const int bcs = (t & 7) * 8;

    const float* aG = adj + (row0 + ar0) * (size_t)NN + acs;
    const unsigned short* bG = neighT + (size_t)br0 * NN + bcs;

    int awb[2], bwb[4];
#pragma unroll
    for (int i = 0; i < 2; ++i) {
        int ar = ar0 + 16 * i;
        awb[i] = ((ar * (BK * 2)) + acs * 2) ^ ((ar & 7) << 4);
    }
#pragma unroll
    for (int i = 0; i < 4; ++i) {
        int br = br0 + 32 * i;
        bwb[i] = ((br * (BK * 2)) + bcs * 2) ^ ((br & 7) << 4);
    }

    f32x4 acc[4];
#pragma unroll
    for (int j = 0; j < 4; ++j) acc[j] = (f32x4){0.f, 0.f, 0.f, 0.f};

    float dsum[2] = {0.f, 0.f};

    f32x4 ar_[2];
    u32x4 br_[4];

    char* aL = (char*)a_lds;
    char* bL = (char*)b_lds;

    // prologue: load + stage tile 0 into buf 0
#pragma unroll
    for (int i = 0; i < 2; ++i)
        ar_[i] = __builtin_nontemporal_load((const f32x4*)(aG + (size_t)(16 * i) * NN));
#pragma unroll
    for (int i = 0; i < 4; ++i)
        br_[i] = *(const u32x4*)(bG + (size_t)(32 * i) * NN);
#pragma unroll
    for (int i = 0; i < 2; ++i) {
        f32x4 v = ar_[i];
        dsum[i] += (v[0] + v[1]) + (v[2] + v[3]);
        u16x4 p; p.x = f2bf(v[0]); p.y = f2bf(v[1]); p.z = f2bf(v[2]); p.w = f2bf(v[3]);
        *(u16x4*)(aL + awb[i]) = p;
    }
#pragma unroll
    for (int i = 0; i < 4; ++i)
        *(u32x4*)(bL + bwb[i]) = br_[i];

    int cur = 0;
    for (int kt = 0; kt < NSTEPS; ++kt) {
        const bool pf = (kt + 1 < NSTEPS);
        if (pf) {
            const size_t koff = (size_t)(kt + 1) * BK;
#pragma unroll
            for (int i = 0; i < 2; ++i)
                ar_[i] = __builtin_nontemporal_load((const f32x4*)(aG + (size_t)(16 * i) * NN + koff));
#pragma unroll
            for (int i = 0; i < 4; ++i)
                br_[i] = *(const u32x4*)(bG + (size_t)(32 * i) * NN + koff);
        }
        __syncthreads();   // tile kt staged & everyone done reading buf cur^1
        {
            const char* aB = aL + cur * (BM * BK * 2);
            const char* bB = bL + cur * (128 * BK * 2);
#pragma unroll
            for (int ks = 0; ks < 2; ++ks) {
                bf16x8 af, bfr[4];
                {
                    int r = mt * 16 + (lane & 15);
                    int off = (r * (BK * 2) + ks * 64 + (lane >> 4) * 16) ^ ((r & 7) << 4);
                    af = *(const bf16x8*)(aB + off);
                }
#pragma unroll
                for (int ns = 0; ns < 4; ++ns) {
                    int c = nt * 64 + ns * 16 + (lane & 15);
                    int off = (c * (BK * 2) + ks * 64 + (lane >> 4) * 16) ^ ((c & 7) << 4);
                    bfr[ns] = *(const bf16x8*)(bB + off);
                }
#pragma unroll
                for (int ns = 0; ns < 4; ++ns)
                    acc[ns] = MFMA16(af, bfr[ns], acc[ns]);
            }
        }
        if (pf) {
            char* aW = aL + (cur ^ 1) * (BM * BK * 2);
            char* bW = bL + (cur ^ 1) * (128 * BK * 2);
#pragma unroll
            for (int i = 0; i < 2; ++i) {
                f32x4 v = ar_[i];
                dsum[i] += (v[0] + v[1]) + (v[2] + v[3]);
                u16x4 p; p.x = f2bf(v[0]); p.y = f2bf(v[1]); p.z = f2bf(v[2]); p.w = f2bf(v[3]);
                *(u16x4*)(aW + awb[i]) = p;
            }
#pragma unroll
            for (int i = 0; i < 4; ++i)
                *(u32x4*)(bW + bwb[i]) = br_[i];
        }
        cur ^= 1;
    }

    // ---- degree reduction ----
#pragma unroll
    for (int i = 0; i < 2; ++i)
        atomicAdd(&degp[ar0 + 16 * i], dsum[i]);
    __syncthreads();

    // ---- h = S/deg -> d_lds cols [128,256) ----
    char* dL = (char*)d_lds;
#pragma unroll
    for (int ns = 0; ns < 4; ++ns)
#pragma unroll
        for (int j = 0; j < 4; ++j) {
            int r = mt * 16 + (lane >> 4) * 4 + j;
            int c = 128 + nt * 64 + ns * 16 + (lane & 15);
            float v = acc[ns][j] / (degp[r] + 1.0f);
            int off = (r * 512 + c * 2) ^ ((r & 7) << 4);
            *(unsigned short*)(dL + off) = f2bf(v);
        }

    // ---- features -> d_lds cols [0,128) ----
#pragma unroll
    for (int i = 0; i < 4; ++i) {
        int idx = i * 256 + t;
        int r = idx >> 5;          // 32 float4-slots per 128-f32 row
        int s = idx & 31;
        f32x4 v = *(const f32x4*)(feat + (row0 + r) * 128 + s * 4);
        u16x4 p; p.x = f2bf(v[0]); p.y = f2bf(v[1]); p.z = f2bf(v[2]); p.w = f2bf(v[3]);
        int off = (r * 512 + s * 8) ^ ((r & 7) << 4);
        *(u16x4*)(dL + off) = p;
    }
    __syncthreads();

    // ---- out = data(32x256) @ W^T via MFMA, K=256; W frags straight from global f32 ----
    f32x4 acc2[4];
#pragma unroll
    for (int j = 0; j < 4; ++j) acc2[j] = (f32x4){0.f, 0.f, 0.f, 0.f};

#pragma unroll
    for (int ks = 0; ks < 8; ++ks) {
        bf16x8 af, bfr[4];
        {
            int r = mt * 16 + (lane & 15);
            int off = (r * 512 + ks * 64 + (lane >> 4) * 16) ^ ((r & 7) << 4);
            af = *(const bf16x8*)(dL + off);
        }
#pragma unroll
        for (int ns = 0; ns < 4; ++ns) {
            int c = nt * 64 + ns * 16 + (lane & 15);
            int k0 = ks * 32 + (lane >> 4) * 8;
            f32x4 w0 = *(const f32x4*)(W + (size_t)c * 256 + k0);
            f32x4 w1 = *(const f32x4*)(W + (size_t)c * 256 + k0 + 4);
            u16x8 p;
            p[0] = f2bf(w0[0]); p[1] = f2bf(w0[1]); p[2] = f2bf(w0[2]); p[3] = f2bf(w0[3]);
            p[4] = f2bf(w1[0]); p[5] = f2bf(w1[1]); p[6] = f2bf(w1[2]); p[7] = f2bf(w1[3]);
            bfr[ns] = __builtin_bit_cast(bf16x8, p);
        }
#pragma unroll
        for (int ns = 0; ns < 4; ++ns)
            acc2[ns] = MFMA16(af, bfr[ns], acc2[ns]);
    }

    // ---- store f32 ----
#pragma unroll
    for (int ns = 0; ns < 4; ++ns)
#pragma unroll
        for (int j = 0; j < 4; ++j) {
            int r = mt * 16 + (lane >> 4) * 4 + j;
            int c = nt * 64 + ns * 16 + (lane & 15);
            out[(row0 + r) * 128 + c] = acc2[ns][j];
        }
}

extern "C" void kernel_launch(void* const* d_in, const int* in_sizes, int n_in,
                              void* d_out, int out_size, void* d_ws, size_t ws_size,
                              hipStream_t stream) {
    const float* adj = (const float*)d_in[0];
    const float* feat = (const float*)d_in[1];
    const float* neigh = (const float*)d_in[2];
    const float* W = (const float*)d_in[3];
    float* out = (float*)d_out;
    unsigned short* neighT = (unsigned short*)d_ws;   // 128 x 16384 bf16 = 4 MiB

    prep_transpose<<<NN / 64, 256, 0, stream>>>(neigh, neighT);
    sage_fused<<<NN / BM, 256, 0, stream>>>(adj, feat, neighT, W, out);
}